// Round 4
// baseline (7717.545 us; speedup 1.0000x reference)
//
#include <hip/hip_runtime.h>
#include <hip/hip_bf16.h>
#include <math.h>

// TitanLongTermMemory — round 4.
// Established: inputs are fp32 (round-3 NaN→finite transition with flag=0).
// Theory this round: d_out is ALSO fp32 (reference output dtype), so round 3's
// bf16 writes produced packed-garbage in the first half of the buffer and
// zeros in the second (observed absmax error 5.0 ~ re-paired out values).
// Only change: final GEMM writes float into d_out.

using bf16 = __hip_bfloat16;

__device__ __forceinline__ float ldf(const bf16* p) { return __bfloat162float(*p); }
__device__ __forceinline__ float ldf(const float* p) { return *p; }
__device__ __forceinline__ void stf(bf16* p, float v) { *p = __float2bfloat16(v); }
__device__ __forceinline__ void stf(float* p, float v) { *p = v; }
__device__ __forceinline__ float us2f(unsigned short u) {
  union { unsigned int i; float f; } c; c.i = ((unsigned int)u) << 16; return c.f;
}

enum { ACT_NONE = 0, ACT_SILU = 1, ACT_SIGMOID = 2 };

// flag=1 if gn_g (all-ones) is bf16 (word0 != 0), else 0 (fp32).
__global__ void detect_kernel(const unsigned short* g, int* flag) {
  if (threadIdx.x == 0) *flag = (g[0] != 0) ? 1 : 0;
}

// dst[i] = bf16(src[src_off + i]) with src dtype chosen by *flag.
__global__ __launch_bounds__(256) void conv_kernel(
    const void* __restrict__ src, bf16* __restrict__ dst, int n, size_t src_off,
    const int* __restrict__ flag) {
  int i = blockIdx.x * 256 + threadIdx.x;
  if (i >= n) return;
  if (*flag) dst[i] = ((const bf16*)src)[src_off + i];
  else dst[i] = __float2bfloat16(((const float*)src)[src_off + i]);
}

// C[M,N] = act(A[M,K] @ op(B) + bias); op(B)=B[N,K] if TRANS_B else B[K,N].
template <typename TA, typename TC, int ACT, bool TRANS_B>
__global__ __launch_bounds__(256) void gemm_kernel(
    const TA* __restrict__ A, const bf16* __restrict__ B,
    const bf16* __restrict__ bias, TC* __restrict__ C,
    int M, int N, int K)
{
  __shared__ float As[16][68];
  __shared__ float Bs[16][68];
  const int tid = threadIdx.x;
  const int tx = tid & 15;
  const int ty = tid >> 4;
  const int m0 = blockIdx.y * 64;
  const int n0 = blockIdx.x * 64;

  float acc[4][4] = {};

  for (int k0 = 0; k0 < K; k0 += 16) {
#pragma unroll
    for (int i = 0; i < 4; ++i) {
      int e = tid + 256 * i;
      int m = e >> 4, kk = e & 15;
      float v = 0.f;
      if (m0 + m < M) v = ldf(&A[(size_t)(m0 + m) * K + k0 + kk]);
      As[kk][m] = v;
    }
#pragma unroll
    for (int i = 0; i < 4; ++i) {
      int e = tid + 256 * i;
      if (TRANS_B) {
        int n = e >> 4, kk = e & 15;
        float v = 0.f;
        if (n0 + n < N) v = ldf(&B[(size_t)(n0 + n) * K + k0 + kk]);
        Bs[kk][n] = v;
      } else {
        int kk = e >> 6, n = e & 63;
        float v = 0.f;
        if (n0 + n < N) v = ldf(&B[(size_t)(k0 + kk) * N + n0 + n]);
        Bs[kk][n] = v;
      }
    }
    __syncthreads();
#pragma unroll
    for (int kk = 0; kk < 16; ++kk) {
      const float4 av = *reinterpret_cast<const float4*>(&As[kk][ty * 4]);
      const float4 bv = *reinterpret_cast<const float4*>(&Bs[kk][tx * 4]);
      const float a[4] = {av.x, av.y, av.z, av.w};
      const float b[4] = {bv.x, bv.y, bv.z, bv.w};
#pragma unroll
      for (int i = 0; i < 4; ++i)
#pragma unroll
        for (int j = 0; j < 4; ++j) acc[i][j] += a[i] * b[j];
    }
    __syncthreads();
  }

#pragma unroll
  for (int i = 0; i < 4; ++i) {
    int m = m0 + ty * 4 + i;
    if (m >= M) continue;
#pragma unroll
    for (int j = 0; j < 4; ++j) {
      int n = n0 + tx * 4 + j;
      if (n >= N) continue;
      float v = acc[i][j];
      if (bias) v += __bfloat162float(bias[n]);
      if (ACT == ACT_SILU) v = v / (1.f + __expf(-v));
      if (ACT == ACT_SIGMOID) v = 1.f / (1.f + __expf(-v));
      stf(&C[(size_t)m * N + n], v);
    }
  }
}

// Row LayerNorm over width W; optional post-LN add of a bf16 vector.
template <typename TI, typename TO, bool ADD, int W, int BS>
__global__ __launch_bounds__(BS) void ln_kernel(
    const TI* __restrict__ in, const bf16* __restrict__ g, const bf16* __restrict__ b,
    const bf16* __restrict__ addv, TO* __restrict__ out)
{
  __shared__ float red[BS];
  const int row = blockIdx.x;
  const TI* rin = in + (size_t)row * W;
  TO* rout = out + (size_t)row * W;
  const int NP = W / BS;
  float v[NP];
  float s = 0.f;
#pragma unroll
  for (int i = 0; i < NP; ++i) { v[i] = ldf(&rin[threadIdx.x + i * BS]); s += v[i]; }
  red[threadIdx.x] = s; __syncthreads();
  for (int o = BS / 2; o > 0; o >>= 1) {
    if (threadIdx.x < o) red[threadIdx.x] += red[threadIdx.x + o];
    __syncthreads();
  }
  const float mean = red[0] / W;
  __syncthreads();
  float sq = 0.f;
#pragma unroll
  for (int i = 0; i < NP; ++i) { float d = v[i] - mean; sq += d * d; }
  red[threadIdx.x] = sq; __syncthreads();
  for (int o = BS / 2; o > 0; o >>= 1) {
    if (threadIdx.x < o) red[threadIdx.x] += red[threadIdx.x + o];
    __syncthreads();
  }
  const float rstd = rsqrtf(red[0] / W + 1e-5f);
#pragma unroll
  for (int i = 0; i < NP; ++i) {
    int c = threadIdx.x + i * BS;
    float o_ = (v[i] - mean) * rstd * __bfloat162float(g[c]) + __bfloat162float(b[c]);
    if (ADD) o_ += __bfloat162float(addv[c]);
    stf(&rout[c], o_);
  }
}

// One block per (segment, head). T = 64 + 4 + 64 = 132. ~118 KB LDS.
__global__ __launch_bounds__(256) void attn_kernel(
    const bf16* __restrict__ qg, const bf16* __restrict__ krg, const bf16* __restrict__ kxg,
    const bf16* __restrict__ kpg, const bf16* __restrict__ vrg, const bf16* __restrict__ vxg,
    const bf16* __restrict__ vpg, bf16* __restrict__ outg)
{
  const int S = 64, T = 132, HD = 128, C = 1024;
  __shared__ unsigned short qs[64][128];
  __shared__ unsigned short ks[132][128];
  __shared__ unsigned short vs[132][128];
  __shared__ float sc[64][133];

  const int tid = threadIdx.x;
  const int seg = blockIdx.x >> 3;
  const int h = blockIdx.x & 7;
  const unsigned short* q = (const unsigned short*)qg;
  const unsigned short* kr = (const unsigned short*)krg;
  const unsigned short* kx = (const unsigned short*)kxg;
  const unsigned short* kp = (const unsigned short*)kpg;
  const unsigned short* vr = (const unsigned short*)vrg;
  const unsigned short* vx = (const unsigned short*)vxg;
  const unsigned short* vp = (const unsigned short*)vpg;
  const size_t segbase = (size_t)seg * 64 * C + (size_t)h * HD;

  for (int e = tid; e < S * HD; e += 256) {
    int s = e >> 7, d = e & 127;
    qs[s][d] = q[segbase + (size_t)s * C + d];
  }
  for (int e = tid; e < T * HD; e += 256) {
    int t = e >> 7, d = e & 127;
    unsigned short kv, vv;
    if (t < 64) {
      kv = kr[segbase + (size_t)t * C + d];
      vv = vr[segbase + (size_t)t * C + d];
    } else if (t < 68) {
      kv = kp[(size_t)(t - 64) * C + h * HD + d];
      vv = vp[(size_t)(t - 64) * C + h * HD + d];
    } else {
      kv = kx[segbase + (size_t)(t - 68) * C + d];
      vv = vx[segbase + (size_t)(t - 68) * C + d];
    }
    ks[t][d] = kv;
    vs[t][d] = vv;
  }
  __syncthreads();

  const float scale = 0.08838834764831845f;  // 1/sqrt(128)
  for (int p = tid; p < S * T; p += 256) {
    int s = p / T, t = p - s * T;
    float a = 0.f;
#pragma unroll 4
    for (int d = 0; d < HD; ++d) a += us2f(qs[s][d]) * us2f(ks[t][d]);
    sc[s][t] = a * scale;
  }
  __syncthreads();

  if (tid < 64) {
    float mx = -3.0e38f;
    for (int t = 0; t < T; ++t) mx = fmaxf(mx, sc[tid][t]);
    float sum = 0.f;
    for (int t = 0; t < T; ++t) { float e = __expf(sc[tid][t] - mx); sc[tid][t] = e; sum += e; }
    float inv = 1.f / sum;
    for (int t = 0; t < T; ++t) sc[tid][t] *= inv;
  }
  __syncthreads();

  for (int e = tid; e < S * HD; e += 256) {
    int s = e >> 7, d = e & 127;
    float a = 0.f;
#pragma unroll 4
    for (int t = 0; t < T; ++t) a += sc[s][t] * us2f(vs[t][d]);
    outg[segbase + (size_t)s * C + d] = __float2bfloat16(a);
  }
}

// t = gate * ao + x (elementwise)
__global__ __launch_bounds__(256) void combine_kernel(
    const bf16* __restrict__ g, const bf16* __restrict__ a,
    const bf16* __restrict__ x, bf16* __restrict__ o, int n)
{
  int i = blockIdx.x * 256 + threadIdx.x;
  if (i < n)
    o[i] = __float2bfloat16(__bfloat162float(g[i]) * __bfloat162float(a[i]) +
                            __bfloat162float(x[i]));
}

extern "C" void kernel_launch(void* const* d_in, const int* in_sizes, int n_in,
                              void* d_out, int out_size, void* d_ws, size_t ws_size,
                              hipStream_t stream)
{
  (void)n_in; (void)out_size;
  const int R = 16384, Cd = 1024, Md = 128;

  char* ws = (char*)d_ws;
  size_t off = 0;
  auto alloc = [&](size_t bytes) -> void* {
    void* p = ws + off;
    off += (bytes + 255) & ~(size_t)255;
    return p;
  };

  // ---- fixed allocations ----
  int* flag = (int*)alloc(256);
  bf16* nb[30];
  nb[0] = nullptr;  // x handled per-chunk
  for (int i = 1; i < 30; ++i) nb[i] = (bf16*)alloc((size_t)in_sizes[i] * sizeof(bf16));
  bf16* Wqq = (bf16*)alloc((size_t)Cd * Cd * sizeof(bf16));
  bf16* Wkk = (bf16*)alloc((size_t)Cd * Cd * sizeof(bf16));
  bf16* Wvv = (bf16*)alloc((size_t)Cd * Cd * sizeof(bf16));
  bf16* kp  = (bf16*)alloc((size_t)4 * Cd * sizeof(bf16));
  bf16* vp  = (bf16*)alloc((size_t)4 * Cd * sizeof(bf16));
  const size_t fixed_end = off;

  // ---- chunk sizing: 7 bf16 bufs (CR*2048B) + 2 fp32 bufs (CR*512B) ----
  int CR = R;
  while (CR > 512 && (size_t)CR * 15360 + fixed_end + 4096 > ws_size) CR >>= 1;
  const int n_chunks = R / CR;

  const size_t RB = (size_t)CR * Cd * sizeof(bf16);
  bf16* Xc = (bf16*)alloc(RB);
  bf16* A  = (bf16*)alloc(RB);
  bf16* Bb = (bf16*)alloc(RB);
  bf16* Cc = (bf16*)alloc(RB);
  bf16* Dd = (bf16*)alloc(RB);
  bf16* Ee = (bf16*)alloc(RB);
  bf16* Ff = (bf16*)alloc(RB);
  float* h1 = (float*)alloc((size_t)CR * Md * sizeof(float));
  float* h2 = (float*)alloc((size_t)CR * Md * sizeof(float));

  auto grd = [](int M_, int N_) {
    return dim3((unsigned)((N_ + 63) / 64), (unsigned)((M_ + 63) / 64));
  };
  dim3 blk(256);

  // ---- dtype detect + normalize all non-x inputs ----
  detect_kernel<<<1, 64, 0, stream>>>((const unsigned short*)d_in[24], flag);
  for (int i = 1; i < 30; ++i) {
    int n = in_sizes[i];
    conv_kernel<<<dim3((n + 255) / 256), blk, 0, stream>>>(d_in[i], nb[i], n, 0, flag);
  }

  const bf16 *pm = nb[1], *Wq = nb[2], *Wk = nb[3], *Wv = nb[4];
  const bf16 *mem_W1 = nb[5], *mem_b1 = nb[6], *ln1g = nb[7], *ln1b = nb[8];
  const bf16 *mem_W2 = nb[9], *mem_b2 = nb[10], *ln2g = nb[11], *ln2b = nb[12];
  const bf16 *mem_oW = nb[13], *mem_ob = nb[14], *mstate = nb[15];
  const bf16 *mhaWq = nb[16], *mhabq = nb[17], *mhaWk = nb[18], *mhabk = nb[19];
  const bf16 *mhaWv = nb[20], *mhabv = nb[21], *mhaWo = nb[22], *mhabo = nb[23];
  const bf16 *gn_g = nb[24], *gn_b = nb[25], *gateW = nb[26], *gateb = nb[27];
  const bf16 *outW = nb[28], *outb = nb[29];

  // combined second-stage weights + persistent K/V (once)
  gemm_kernel<bf16, bf16, ACT_NONE, false><<<grd(Cd, Cd), blk, 0, stream>>>(mhaWq, Wq, nullptr, Wqq, Cd, Cd, Cd);
  gemm_kernel<bf16, bf16, ACT_NONE, false><<<grd(Cd, Cd), blk, 0, stream>>>(mhaWk, Wk, nullptr, Wkk, Cd, Cd, Cd);
  gemm_kernel<bf16, bf16, ACT_NONE, false><<<grd(Cd, Cd), blk, 0, stream>>>(mhaWv, Wv, nullptr, Wvv, Cd, Cd, Cd);
  gemm_kernel<bf16, bf16, ACT_NONE, true><<<grd(4, Cd), blk, 0, stream>>>(pm, Wkk, mhabk, kp, 4, Cd, Cd);
  gemm_kernel<bf16, bf16, ACT_NONE, true><<<grd(4, Cd), blk, 0, stream>>>(pm, Wvv, mhabv, vp, 4, Cd, Cd);

  for (int c = 0; c < n_chunks; ++c) {
    float* outc = (float*)d_out + (size_t)c * CR * Cd;   // fp32 OUTPUT
    const int n = CR * Cd;
    // normalize this x chunk (element offset works for both dtypes)
    conv_kernel<<<dim3((n + 255) / 256), blk, 0, stream>>>(
        d_in[0], Xc, n, (size_t)c * CR * Cd, flag);

    // q_seg = Xc @ Wq^T  -> memory net -> retrieved (Bb)
    gemm_kernel<bf16, bf16, ACT_NONE, true><<<grd(CR, Cd), blk, 0, stream>>>(Xc, Wq, nullptr, A, CR, Cd, Cd);
    gemm_kernel<bf16, float, ACT_SILU, true><<<grd(CR, Md), blk, 0, stream>>>(A, mem_W1, mem_b1, h1, CR, Md, Cd);
    ln_kernel<float, float, false, 128, 128><<<CR, 128, 0, stream>>>(h1, ln1g, ln1b, nullptr, h2);
    gemm_kernel<float, float, ACT_NONE, true><<<grd(CR, Md), blk, 0, stream>>>(h2, mem_W2, mem_b2, h1, CR, Md, Md);
    ln_kernel<float, float, true, 128, 128><<<CR, 128, 0, stream>>>(h1, ln2g, ln2b, mstate, h2);
    gemm_kernel<float, bf16, ACT_NONE, true><<<grd(CR, Cd), blk, 0, stream>>>(h2, mem_oW, mem_ob, Bb, CR, Cd, Md);

    // fused QKV projections
    gemm_kernel<bf16, bf16, ACT_NONE, true><<<grd(CR, Cd), blk, 0, stream>>>(Xc, Wqq, mhabq, A, CR, Cd, Cd);   // q
    gemm_kernel<bf16, bf16, ACT_NONE, true><<<grd(CR, Cd), blk, 0, stream>>>(Bb, Wkk, mhabk, Cc, CR, Cd, Cd);  // k_r
    gemm_kernel<bf16, bf16, ACT_NONE, true><<<grd(CR, Cd), blk, 0, stream>>>(Bb, Wvv, mhabv, Dd, CR, Cd, Cd);  // v_r
    gemm_kernel<bf16, bf16, ACT_NONE, true><<<grd(CR, Cd), blk, 0, stream>>>(Xc, Wkk, mhabk, Ee, CR, Cd, Cd);  // k_x
    gemm_kernel<bf16, bf16, ACT_NONE, true><<<grd(CR, Cd), blk, 0, stream>>>(Xc, Wvv, mhabv, Ff, CR, Cd, Cd);  // v_x

    attn_kernel<<<dim3((CR / 64) * 8), blk, 0, stream>>>(A, Cc, Ee, kp, Dd, Ff, vp, Bb);

    // output projection, gate, final (fp32 store to d_out)
    gemm_kernel<bf16, bf16, ACT_NONE, true><<<grd(CR, Cd), blk, 0, stream>>>(Bb, mhaWo, mhabo, A, CR, Cd, Cd);     // ao
    ln_kernel<bf16, bf16, false, 1024, 256><<<CR, 256, 0, stream>>>(A, gn_g, gn_b, nullptr, Cc);                   // gin
    gemm_kernel<bf16, bf16, ACT_SIGMOID, true><<<grd(CR, Cd), blk, 0, stream>>>(Cc, gateW, gateb, Dd, CR, Cd, Cd); // gate
    combine_kernel<<<dim3(n / 256), blk, 0, stream>>>(Dd, A, Xc, Cc, n);                                           // t
    gemm_kernel<bf16, float, ACT_NONE, true><<<grd(CR, Cd), blk, 0, stream>>>(Cc, outW, outb, outc, CR, Cd, Cd);
  }
}

// Round 5
// 1591.660 us; speedup vs baseline: 4.8487x; 4.8487x over previous
//
#include <hip/hip_runtime.h>
#include <hip/hip_bf16.h>
#include <math.h>

// TitanLongTermMemory — round 5: MFMA GEMM (m97-style) + attention LDS fixes.
// Established: inputs fp32, output fp32, ws-adaptive chunking works.
// r4 profile: attn 880us/chunk (2.7e8 LDS bank conflicts, 32-way on ks reads),
// GEMMs ~5.9ms on VALU (MfmaUtil=0). This round: mfma_f32_16x16x32_bf16 GEMM
// with global_load_lds(16B) staging; attn padded LDS + 4x4 register blocking.

using bf16 = __hip_bfloat16;

typedef __attribute__((ext_vector_type(8))) short bf16x8;
typedef __attribute__((ext_vector_type(4))) float f32x4;

__device__ __forceinline__ float ldf(const bf16* p) { return __bfloat162float(*p); }
__device__ __forceinline__ float ldf(const float* p) { return *p; }
__device__ __forceinline__ void stf(bf16* p, float v) { *p = __float2bfloat16(v); }
__device__ __forceinline__ void stf(float* p, float v) { *p = v; }
__device__ __forceinline__ float us2f(unsigned int u) {
  union { unsigned int i; float f; } c; c.i = u << 16; return c.f;
}
__device__ __forceinline__ float b2f(const bf16& b) { return __bfloat162float(b); }

enum { ACT_NONE = 0, ACT_SILU = 1, ACT_SIGMOID = 2 };

// flag=1 if gn_g (all-ones) is bf16 (word0 != 0), else 0 (fp32).
__global__ void detect_kernel(const unsigned short* g, int* flag) {
  if (threadIdx.x == 0) *flag = (g[0] != 0) ? 1 : 0;
}

// dst[i] = bf16(src[src_off + i]) with src dtype chosen by *flag.
__global__ __launch_bounds__(256) void conv_kernel(
    const void* __restrict__ src, bf16* __restrict__ dst, int n, size_t src_off,
    const int* __restrict__ flag) {
  int i = blockIdx.x * 256 + threadIdx.x;
  if (i >= n) return;
  if (*flag) dst[i] = ((const bf16*)src)[src_off + i];
  else dst[i] = __float2bfloat16(((const float*)src)[src_off + i]);
}

// ---------------- MFMA GEMM: C[M,N] = act(A[M,K] @ B[N,K]^T + bias) ----------
// M,N multiples of 128 or N==128; K multiple of 32. 256 threads, 4 waves,
// each wave computes 64x64 via 4x4 mfma_f32_16x16x32_bf16 tiles.
__device__ __forceinline__ void gl_lds16(const short* g, short* l) {
  __builtin_amdgcn_global_load_lds(
      (const __attribute__((address_space(1))) void*)g,
      (__attribute__((address_space(3))) void*)l, 16, 0, 0);
}

template <typename TC, int ACT, bool HAS_BIAS>
__global__ __launch_bounds__(256) void mgemm(
    const bf16* __restrict__ Ab, const bf16* __restrict__ Bw,
    const bf16* __restrict__ bias, TC* __restrict__ C,
    int M, int N, int K)
{
  __shared__ short As[128 * 32];
  __shared__ short Bs[128 * 32];
  const short* A = (const short*)Ab;
  const short* B = (const short*)Bw;
  const int tid = threadIdx.x;
  const int m0 = blockIdx.y * 128, n0 = blockIdx.x * 128;
  const int wave = tid >> 6, lane = tid & 63;
  const int wm = (wave & 1) * 64, wn = (wave >> 1) * 64;
  const int fm = lane & 15;        // fragment row (A) / col (B)
  const int fk = (lane >> 4) * 8;  // fragment k offset

  // staging addresses: flat element e covers LDS [0..255]*16B (rows 0..63 of
  // the 128x32 tile per issue); global row = flat>>2, k-byte = (flat&3)*16.
  const int srow = tid >> 2, scol = (tid & 3) * 8;
  const short* gA0 = A + (size_t)(m0 + srow) * K + scol;
  const short* gA1 = A + (size_t)(m0 + 64 + srow) * K + scol;
  const short* gB0 = B + (size_t)(n0 + srow) * K + scol;
  const short* gB1 = B + (size_t)(n0 + 64 + srow) * K + scol;
  short* lA0 = As + tid * 8;
  short* lA1 = As + (256 + tid) * 8;
  short* lB0 = Bs + tid * 8;
  short* lB1 = Bs + (256 + tid) * 8;

  f32x4 acc[4][4] = {};

  for (int k0 = 0; k0 < K; k0 += 32) {
    gl_lds16(gA0 + k0, lA0);
    gl_lds16(gA1 + k0, lA1);
    gl_lds16(gB0 + k0, lB0);
    gl_lds16(gB1 + k0, lB1);
    __syncthreads();
    bf16x8 af[4], bfr[4];
#pragma unroll
    for (int i = 0; i < 4; ++i)
      af[i] = *(const bf16x8*)&As[(wm + i * 16 + fm) * 32 + fk];
#pragma unroll
    for (int j = 0; j < 4; ++j)
      bfr[j] = *(const bf16x8*)&Bs[(wn + j * 16 + fm) * 32 + fk];
#pragma unroll
    for (int i = 0; i < 4; ++i)
#pragma unroll
      for (int j = 0; j < 4; ++j)
        acc[i][j] = __builtin_amdgcn_mfma_f32_16x16x32_bf16(af[i], bfr[j], acc[i][j], 0, 0, 0);
    __syncthreads();
  }

  // C/D layout: col = lane&15, row = (lane>>4)*4 + r  (m89-verified)
  const int rg = (lane >> 4) * 4;
#pragma unroll
  for (int i = 0; i < 4; ++i) {
#pragma unroll
    for (int j = 0; j < 4; ++j) {
      const int n = n0 + wn + j * 16 + fm;
      float bv = 0.f;
      if (HAS_BIAS) bv = b2f(bias[n]);
#pragma unroll
      for (int r = 0; r < 4; ++r) {
        const int m = m0 + wm + i * 16 + rg + r;
        float v = acc[i][j][r] + bv;
        if (ACT == ACT_SILU) v = v / (1.f + __expf(-v));
        if (ACT == ACT_SIGMOID) v = 1.f / (1.f + __expf(-v));
        stf(&C[(size_t)m * N + n], v);
      }
    }
  }
}

// ---------------- fallback VALU GEMM (weight combines, 4-row kp/vp) ----------
template <typename TA, typename TC, int ACT, bool TRANS_B>
__global__ __launch_bounds__(256) void gemm_kernel(
    const TA* __restrict__ A, const bf16* __restrict__ B,
    const bf16* __restrict__ bias, TC* __restrict__ C,
    int M, int N, int K)
{
  __shared__ float As[16][68];
  __shared__ float Bs[16][68];
  const int tid = threadIdx.x;
  const int tx = tid & 15;
  const int ty = tid >> 4;
  const int m0 = blockIdx.y * 64;
  const int n0 = blockIdx.x * 64;

  float acc[4][4] = {};

  for (int k0 = 0; k0 < K; k0 += 16) {
#pragma unroll
    for (int i = 0; i < 4; ++i) {
      int e = tid + 256 * i;
      int m = e >> 4, kk = e & 15;
      float v = 0.f;
      if (m0 + m < M) v = ldf(&A[(size_t)(m0 + m) * K + k0 + kk]);
      As[kk][m] = v;
    }
#pragma unroll
    for (int i = 0; i < 4; ++i) {
      int e = tid + 256 * i;
      if (TRANS_B) {
        int n = e >> 4, kk = e & 15;
        float v = 0.f;
        if (n0 + n < N) v = ldf(&B[(size_t)(n0 + n) * K + k0 + kk]);
        Bs[kk][n] = v;
      } else {
        int kk = e >> 6, n = e & 63;
        float v = 0.f;
        if (n0 + n < N) v = ldf(&B[(size_t)(k0 + kk) * N + n0 + n]);
        Bs[kk][n] = v;
      }
    }
    __syncthreads();
#pragma unroll
    for (int kk = 0; kk < 16; ++kk) {
      const float4 av = *reinterpret_cast<const float4*>(&As[kk][ty * 4]);
      const float4 bv = *reinterpret_cast<const float4*>(&Bs[kk][tx * 4]);
      const float a[4] = {av.x, av.y, av.z, av.w};
      const float b[4] = {bv.x, bv.y, bv.z, bv.w};
#pragma unroll
      for (int i = 0; i < 4; ++i)
#pragma unroll
        for (int j = 0; j < 4; ++j) acc[i][j] += a[i] * b[j];
    }
    __syncthreads();
  }

#pragma unroll
  for (int i = 0; i < 4; ++i) {
    int m = m0 + ty * 4 + i;
    if (m >= M) continue;
#pragma unroll
    for (int j = 0; j < 4; ++j) {
      int n = n0 + tx * 4 + j;
      if (n >= N) continue;
      float v = acc[i][j];
      if (bias) v += b2f(bias[n]);
      if (ACT == ACT_SILU) v = v / (1.f + __expf(-v));
      if (ACT == ACT_SIGMOID) v = 1.f / (1.f + __expf(-v));
      stf(&C[(size_t)m * N + n], v);
    }
  }
}

// Row LayerNorm over width W; optional post-LN add of a bf16 vector.
template <typename TI, typename TO, bool ADD, int W, int BS>
__global__ __launch_bounds__(BS) void ln_kernel(
    const TI* __restrict__ in, const bf16* __restrict__ g, const bf16* __restrict__ b,
    const bf16* __restrict__ addv, TO* __restrict__ out)
{
  __shared__ float red[BS];
  const int row = blockIdx.x;
  const TI* rin = in + (size_t)row * W;
  TO* rout = out + (size_t)row * W;
  const int NP = W / BS;
  float v[NP];
  float s = 0.f;
#pragma unroll
  for (int i = 0; i < NP; ++i) { v[i] = ldf(&rin[threadIdx.x + i * BS]); s += v[i]; }
  red[threadIdx.x] = s; __syncthreads();
  for (int o = BS / 2; o > 0; o >>= 1) {
    if (threadIdx.x < o) red[threadIdx.x] += red[threadIdx.x + o];
    __syncthreads();
  }
  const float mean = red[0] / W;
  __syncthreads();
  float sq = 0.f;
#pragma unroll
  for (int i = 0; i < NP; ++i) { float d = v[i] - mean; sq += d * d; }
  red[threadIdx.x] = sq; __syncthreads();
  for (int o = BS / 2; o > 0; o >>= 1) {
    if (threadIdx.x < o) red[threadIdx.x] += red[threadIdx.x + o];
    __syncthreads();
  }
  const float rstd = rsqrtf(red[0] / W + 1e-5f);
#pragma unroll
  for (int i = 0; i < NP; ++i) {
    int c = threadIdx.x + i * BS;
    float o_ = (v[i] - mean) * rstd * b2f(g[c]) + b2f(b[c]);
    if (ADD) o_ += b2f(addv[c]);
    stf(&rout[c], o_);
  }
}

// ---------------- attention: one block per (segment, head) ------------------
// T = 64 (retrieved) + 4 (persistent) + 64 (xs) = 132. Padded LDS rows kill
// the r4 32-way bank conflicts; 4x4 register blocking cuts LDS reads 4x.
__global__ __launch_bounds__(512) void attn_kernel(
    const bf16* __restrict__ qg, const bf16* __restrict__ krg, const bf16* __restrict__ kxg,
    const bf16* __restrict__ kpg, const bf16* __restrict__ vrg, const bf16* __restrict__ vxg,
    const bf16* __restrict__ vpg, bf16* __restrict__ outg)
{
  const int S = 64, T = 132, HD = 128, C = 1024;
  __shared__ unsigned short qs[64][130];   // 260B rows: bank stride 65 dw -> conflict-free
  __shared__ unsigned short ks[132][130];
  __shared__ unsigned short vs[132][132];  // 264B rows: 8B-aligned for uint2 reads
  __shared__ float sc[64][134];            // 536B rows: 8B-aligned for float2 reads

  const int tid = threadIdx.x;
  const int seg = blockIdx.x >> 3;
  const int h = blockIdx.x & 7;
  const unsigned short* q = (const unsigned short*)qg;
  const unsigned short* kr = (const unsigned short*)krg;
  const unsigned short* kx = (const unsigned short*)kxg;
  const unsigned short* kp = (const unsigned short*)kpg;
  const unsigned short* vr = (const unsigned short*)vrg;
  const unsigned short* vx = (const unsigned short*)vxg;
  const unsigned short* vp = (const unsigned short*)vpg;
  const size_t segbase = (size_t)seg * 64 * C + (size_t)h * HD;

  for (int e = tid; e < S * HD; e += 512) {
    int s = e >> 7, d = e & 127;
    qs[s][d] = q[segbase + (size_t)s * C + d];
  }
  for (int e = tid; e < T * HD; e += 512) {
    int t = e >> 7, d = e & 127;
    unsigned short kv, vv;
    if (t < 64) {
      kv = kr[segbase + (size_t)t * C + d];
      vv = vr[segbase + (size_t)t * C + d];
    } else if (t < 68) {
      kv = kp[(size_t)(t - 64) * C + h * HD + d];
      vv = vp[(size_t)(t - 64) * C + h * HD + d];
    } else {
      kv = kx[segbase + (size_t)(t - 68) * C + d];
      vv = vx[segbase + (size_t)(t - 68) * C + d];
    }
    ks[t][d] = kv;
    vs[t][d] = vv;
  }
  __syncthreads();

  const float scale = 0.08838834764831845f;  // 1/sqrt(128)
  // QK^T: 4x4 tiles; 16*33 = 528 tiles over 512 threads
  for (int idx = tid; idx < 16 * 33; idx += 512) {
    const int s0 = (idx / 33) * 4, t0 = (idx % 33) * 4;
    float acc[4][4] = {};
    for (int d = 0; d < HD; d += 2) {
      unsigned int qw[4], kw[4];
#pragma unroll
      for (int i = 0; i < 4; ++i) qw[i] = *(const unsigned int*)&qs[s0 + i][d];
#pragma unroll
      for (int j = 0; j < 4; ++j) kw[j] = *(const unsigned int*)&ks[t0 + j][d];
#pragma unroll
      for (int i = 0; i < 4; ++i) {
        const float qlo = us2f(qw[i] & 0xffffu), qhi = us2f(qw[i] >> 16);
#pragma unroll
        for (int j = 0; j < 4; ++j)
          acc[i][j] += qlo * us2f(kw[j] & 0xffffu) + qhi * us2f(kw[j] >> 16);
      }
    }
#pragma unroll
    for (int i = 0; i < 4; ++i)
#pragma unroll
      for (int j = 0; j < 4; ++j) sc[s0 + i][t0 + j] = acc[i][j] * scale;
  }
  __syncthreads();

  if (tid < 64) {
    float mx = -3.0e38f;
    for (int t = 0; t < T; ++t) mx = fmaxf(mx, sc[tid][t]);
    float sum = 0.f;
    for (int t = 0; t < T; ++t) { float e = __expf(sc[tid][t] - mx); sc[tid][t] = e; sum += e; }
    float inv = 1.f / sum;
    for (int t = 0; t < T; ++t) sc[tid][t] *= inv;
  }
  __syncthreads();

  // P@V: 4s x 4d tiles, t-step 2; 16*32 = 512 tiles over 512 threads
  for (int idx = tid; idx < 16 * 32; idx += 512) {
    const int s0 = (idx >> 5) * 4, d0 = (idx & 31) * 4;
    float acc[4][4] = {};
    for (int t = 0; t < T; t += 2) {
      float2 p[4];
#pragma unroll
      for (int i = 0; i < 4; ++i) p[i] = *(const float2*)&sc[s0 + i][t];
      const uint2 w0 = *(const uint2*)&vs[t][d0];
      const uint2 w1 = *(const uint2*)&vs[t + 1][d0];
      float v0[4], v1[4];
      v0[0] = us2f(w0.x & 0xffffu); v0[1] = us2f(w0.x >> 16);
      v0[2] = us2f(w0.y & 0xffffu); v0[3] = us2f(w0.y >> 16);
      v1[0] = us2f(w1.x & 0xffffu); v1[1] = us2f(w1.x >> 16);
      v1[2] = us2f(w1.y & 0xffffu); v1[3] = us2f(w1.y >> 16);
#pragma unroll
      for (int i = 0; i < 4; ++i)
#pragma unroll
        for (int k = 0; k < 4; ++k)
          acc[i][k] += p[i].x * v0[k] + p[i].y * v1[k];
    }
#pragma unroll
    for (int i = 0; i < 4; ++i)
#pragma unroll
      for (int k = 0; k < 4; ++k)
        outg[segbase + (size_t)(s0 + i) * C + d0 + k] = __float2bfloat16(acc[i][k]);
  }
}

// t = gate * ao + x (elementwise)
__global__ __launch_bounds__(256) void combine_kernel(
    const bf16* __restrict__ g, const bf16* __restrict__ a,
    const bf16* __restrict__ x, bf16* __restrict__ o, int n)
{
  int i = blockIdx.x * 256 + threadIdx.x;
  if (i < n)
    o[i] = __float2bfloat16(b2f(g[i]) * b2f(a[i]) + b2f(x[i]));
}

extern "C" void kernel_launch(void* const* d_in, const int* in_sizes, int n_in,
                              void* d_out, int out_size, void* d_ws, size_t ws_size,
                              hipStream_t stream)
{
  (void)n_in; (void)out_size;
  const int R = 16384, Cd = 1024, Md = 128;

  char* ws = (char*)d_ws;
  size_t off = 0;
  auto alloc = [&](size_t bytes) -> void* {
    void* p = ws + off;
    off += (bytes + 255) & ~(size_t)255;
    return p;
  };

  // ---- fixed allocations ----
  int* flag = (int*)alloc(256);
  bf16* nb[30];
  nb[0] = nullptr;  // x handled per-chunk
  for (int i = 1; i < 30; ++i) nb[i] = (bf16*)alloc((size_t)in_sizes[i] * sizeof(bf16));
  bf16* Wkk = (bf16*)alloc((size_t)Cd * Cd * sizeof(bf16));
  bf16* Wvv = (bf16*)alloc((size_t)Cd * Cd * sizeof(bf16));
  bf16* kp  = (bf16*)alloc((size_t)4 * Cd * sizeof(bf16));
  bf16* vp  = (bf16*)alloc((size_t)4 * Cd * sizeof(bf16));
  const size_t fixed_end = off;

  // ---- chunk sizing: 7 bf16 token bufs + 2 bf16 M-bufs = 14848 B/row ----
  int CR = R;
  while (CR > 512 && (size_t)CR * 14848 + fixed_end + 8192 > ws_size) CR >>= 1;
  const int n_chunks = R / CR;

  const size_t RB = (size_t)CR * Cd * sizeof(bf16);
  bf16* Xc = (bf16*)alloc(RB);
  bf16* A  = (bf16*)alloc(RB);   // q_seg -> v_x
  bf16* Bb = (bf16*)alloc(RB);   // retrieved -> attn out
  bf16* Cc = (bf16*)alloc(RB);   // k_r -> gin -> t
  bf16* Dd = (bf16*)alloc(RB);   // v_r -> gate
  bf16* Ee = (bf16*)alloc(RB);   // k_x
  bf16* G  = (bf16*)alloc(RB);   // q -> ao
  bf16* h1b = (bf16*)alloc((size_t)CR * Md * sizeof(bf16));
  bf16* h2b = (bf16*)alloc((size_t)CR * Md * sizeof(bf16));

  auto grd64 = [](int M_, int N_) {
    return dim3((unsigned)((N_ + 63) / 64), (unsigned)((M_ + 63) / 64));
  };
  auto grd128 = [](int M_, int N_) {
    return dim3((unsigned)(N_ / 128), (unsigned)(M_ / 128));
  };
  dim3 blk(256);

  // ---- dtype detect + normalize all non-x inputs ----
  detect_kernel<<<1, 64, 0, stream>>>((const unsigned short*)d_in[24], flag);
  for (int i = 1; i < 30; ++i) {
    int n = in_sizes[i];
    conv_kernel<<<dim3((n + 255) / 256), blk, 0, stream>>>(d_in[i], nb[i], n, 0, flag);
  }

  const bf16 *pm = nb[1], *Wq = nb[2], *Wk = nb[3], *Wv = nb[4];
  const bf16 *mem_W1 = nb[5], *mem_b1 = nb[6], *ln1g = nb[7], *ln1b = nb[8];
  const bf16 *mem_W2 = nb[9], *mem_b2 = nb[10], *ln2g = nb[11], *ln2b = nb[12];
  const bf16 *mem_oW = nb[13], *mem_ob = nb[14], *mstate = nb[15];
  const bf16 *mhaWq = nb[16], *mhabq = nb[17], *mhaWk = nb[18], *mhabk = nb[19];
  const bf16 *mhaWv = nb[20], *mhabv = nb[21], *mhaWo = nb[22], *mhabo = nb[23];
  const bf16 *gn_g = nb[24], *gn_b = nb[25], *gateW = nb[26], *gateb = nb[27];
  const bf16 *outW = nb[28], *outb = nb[29];

  // combined K/V weights + persistent rows (VALU kernel; small / M=4)
  gemm_kernel<bf16, bf16, ACT_NONE, false><<<grd64(Cd, Cd), blk, 0, stream>>>(mhaWk, Wk, nullptr, Wkk, Cd, Cd, Cd);
  gemm_kernel<bf16, bf16, ACT_NONE, false><<<grd64(Cd, Cd), blk, 0, stream>>>(mhaWv, Wv, nullptr, Wvv, Cd, Cd, Cd);
  gemm_kernel<bf16, bf16, ACT_NONE, true><<<grd64(4, Cd), blk, 0, stream>>>(pm, Wkk, mhabk, kp, 4, Cd, Cd);
  gemm_kernel<bf16, bf16, ACT_NONE, true><<<grd64(4, Cd), blk, 0, stream>>>(pm, Wvv, mhabv, vp, 4, Cd, Cd);

  for (int c = 0; c < n_chunks; ++c) {
    float* outc = (float*)d_out + (size_t)c * CR * Cd;
    const int n = CR * Cd;
    conv_kernel<<<dim3((n + 255) / 256), blk, 0, stream>>>(
        d_in[0], Xc, n, (size_t)c * CR * Cd, flag);

    // q_seg -> memory net -> retrieved (Bb)
    mgemm<bf16, ACT_NONE, false><<<grd128(CR, Cd), blk, 0, stream>>>(Xc, Wq, nullptr, A, CR, Cd, Cd);
    mgemm<bf16, ACT_SILU, true><<<grd128(CR, Md), blk, 0, stream>>>(A, mem_W1, mem_b1, h1b, CR, Md, Cd);
    ln_kernel<bf16, bf16, false, 128, 128><<<CR, 128, 0, stream>>>(h1b, ln1g, ln1b, nullptr, h2b);
    mgemm<bf16, ACT_NONE, true><<<grd128(CR, Md), blk, 0, stream>>>(h2b, mem_W2, mem_b2, h1b, CR, Md, Md);
    ln_kernel<bf16, bf16, true, 128, 128><<<CR, 128, 0, stream>>>(h1b, ln2g, ln2b, mstate, h2b);
    mgemm<bf16, ACT_NONE, true><<<grd128(CR, Cd), blk, 0, stream>>>(h2b, mem_oW, mem_ob, Bb, CR, Cd, Md);

    // QKV projections (q via q_seg: (x@Wq^T)@mhaWq^T == x@(mhaWq@Wq)^T)
    mgemm<bf16, ACT_NONE, true><<<grd128(CR, Cd), blk, 0, stream>>>(A, mhaWq, mhabq, G, CR, Cd, Cd);   // q
    mgemm<bf16, ACT_NONE, true><<<grd128(CR, Cd), blk, 0, stream>>>(Bb, Wkk, mhabk, Cc, CR, Cd, Cd);   // k_r
    mgemm<bf16, ACT_NONE, true><<<grd128(CR, Cd), blk, 0, stream>>>(Bb, Wvv, mhabv, Dd, CR, Cd, Cd);   // v_r
    mgemm<bf16, ACT_NONE, true><<<grd128(CR, Cd), blk, 0, stream>>>(Xc, Wkk, mhabk, Ee, CR, Cd, Cd);   // k_x
    mgemm<bf16, ACT_NONE, true><<<grd128(CR, Cd), blk, 0, stream>>>(Xc, Wvv, mhabv, A, CR, Cd, Cd);    // v_x (A dead)

    attn_kernel<<<dim3((CR / 64) * 8), dim3(512), 0, stream>>>(G, Cc, Ee, kp, Dd, A, vp, Bb);

    // output projection, gate, final (fp32 store to d_out)
    mgemm<bf16, ACT_NONE, true><<<grd128(CR, Cd), blk, 0, stream>>>(Bb, mhaWo, mhabo, G, CR, Cd, Cd);      // ao
    ln_kernel<bf16, bf16, false, 1024, 256><<<CR, 256, 0, stream>>>(G, gn_g, gn_b, nullptr, Cc);           // gin
    mgemm<bf16, ACT_SIGMOID, true><<<grd128(CR, Cd), blk, 0, stream>>>(Cc, gateW, gateb, Dd, CR, Cd, Cd);  // gate
    combine_kernel<<<dim3(n / 256), blk, 0, stream>>>(Dd, G, Xc, Cc, n);                                   // t
    mgemm<float, ACT_NONE, true><<<grd128(CR, Cd), blk, 0, stream>>>(Cc, outW, outb, outc, CR, Cd, Cd);
  }
}

// Round 6
// 1418.695 us; speedup vs baseline: 5.4399x; 1.1219x over previous
//
#include <hip/hip_runtime.h>
#include <hip/hip_bf16.h>
#include <math.h>

// TitanLongTermMemory — round 6: MFMA attention.
// r5: attn = 317us x4 chunks = ~80% of 1592us total, MfmaUtil=0 (VALU QK/PV).
// This round: per-(seg,head) block attention with mfma_f32_16x16x32_bf16 for
// both QK^T and PV; scores live in registers; softmax via quad shfl_xor;
// P -> bf16 LDS tiles -> PV A-frags. T padded 132->160 (masked / zero-filled).

using bf16 = __hip_bfloat16;

typedef __attribute__((ext_vector_type(8))) short bf16x8;
typedef __attribute__((ext_vector_type(4))) float f32x4;

__device__ __forceinline__ float ldf(const bf16* p) { return __bfloat162float(*p); }
__device__ __forceinline__ float ldf(const float* p) { return *p; }
__device__ __forceinline__ void stf(bf16* p, float v) { *p = __float2bfloat16(v); }
__device__ __forceinline__ void stf(float* p, float v) { *p = v; }
__device__ __forceinline__ float b2f(const bf16& b) { return __bfloat162float(b); }

enum { ACT_NONE = 0, ACT_SILU = 1, ACT_SIGMOID = 2 };

// flag=1 if gn_g (all-ones) is bf16 (word0 != 0), else 0 (fp32).
__global__ void detect_kernel(const unsigned short* g, int* flag) {
  if (threadIdx.x == 0) *flag = (g[0] != 0) ? 1 : 0;
}

__global__ __launch_bounds__(256) void conv_kernel(
    const void* __restrict__ src, bf16* __restrict__ dst, int n, size_t src_off,
    const int* __restrict__ flag) {
  int i = blockIdx.x * 256 + threadIdx.x;
  if (i >= n) return;
  if (*flag) dst[i] = ((const bf16*)src)[src_off + i];
  else dst[i] = __float2bfloat16(((const float*)src)[src_off + i]);
}

// ---------------- MFMA GEMM: C[M,N] = act(A[M,K] @ B[N,K]^T + bias) ----------
__device__ __forceinline__ void gl_lds16(const short* g, short* l) {
  __builtin_amdgcn_global_load_lds(
      (const __attribute__((address_space(1))) void*)g,
      (__attribute__((address_space(3))) void*)l, 16, 0, 0);
}

template <typename TC, int ACT, bool HAS_BIAS>
__global__ __launch_bounds__(256) void mgemm(
    const bf16* __restrict__ Ab, const bf16* __restrict__ Bw,
    const bf16* __restrict__ bias, TC* __restrict__ C,
    int M, int N, int K)
{
  __shared__ short As[128 * 32];
  __shared__ short Bs[128 * 32];
  const short* A = (const short*)Ab;
  const short* B = (const short*)Bw;
  const int tid = threadIdx.x;
  const int m0 = blockIdx.y * 128, n0 = blockIdx.x * 128;
  const int wave = tid >> 6, lane = tid & 63;
  const int wm = (wave & 1) * 64, wn = (wave >> 1) * 64;
  const int fm = lane & 15;
  const int fk = (lane >> 4) * 8;

  const int srow = tid >> 2, scol = (tid & 3) * 8;
  const short* gA0 = A + (size_t)(m0 + srow) * K + scol;
  const short* gA1 = A + (size_t)(m0 + 64 + srow) * K + scol;
  const short* gB0 = B + (size_t)(n0 + srow) * K + scol;
  const short* gB1 = B + (size_t)(n0 + 64 + srow) * K + scol;
  short* lA0 = As + tid * 8;
  short* lA1 = As + (256 + tid) * 8;
  short* lB0 = Bs + tid * 8;
  short* lB1 = Bs + (256 + tid) * 8;

  f32x4 acc[4][4] = {};

  for (int k0 = 0; k0 < K; k0 += 32) {
    gl_lds16(gA0 + k0, lA0);
    gl_lds16(gA1 + k0, lA1);
    gl_lds16(gB0 + k0, lB0);
    gl_lds16(gB1 + k0, lB1);
    __syncthreads();
    bf16x8 af[4], bfr[4];
#pragma unroll
    for (int i = 0; i < 4; ++i)
      af[i] = *(const bf16x8*)&As[(wm + i * 16 + fm) * 32 + fk];
#pragma unroll
    for (int j = 0; j < 4; ++j)
      bfr[j] = *(const bf16x8*)&Bs[(wn + j * 16 + fm) * 32 + fk];
#pragma unroll
    for (int i = 0; i < 4; ++i)
#pragma unroll
      for (int j = 0; j < 4; ++j)
        acc[i][j] = __builtin_amdgcn_mfma_f32_16x16x32_bf16(af[i], bfr[j], acc[i][j], 0, 0, 0);
    __syncthreads();
  }

  const int rg = (lane >> 4) * 4;
#pragma unroll
  for (int i = 0; i < 4; ++i) {
#pragma unroll
    for (int j = 0; j < 4; ++j) {
      const int n = n0 + wn + j * 16 + fm;
      float bv = 0.f;
      if (HAS_BIAS) bv = b2f(bias[n]);
#pragma unroll
      for (int r = 0; r < 4; ++r) {
        const int m = m0 + wm + i * 16 + rg + r;
        float v = acc[i][j][r] + bv;
        if (ACT == ACT_SILU) v = v / (1.f + __expf(-v));
        if (ACT == ACT_SIGMOID) v = 1.f / (1.f + __expf(-v));
        stf(&C[(size_t)m * N + n], v);
      }
    }
  }
}

// ---------------- VALU GEMM (weight combines, M=4 rows) ----------------------
template <typename TA, typename TC, int ACT, bool TRANS_B>
__global__ __launch_bounds__(256) void gemm_kernel(
    const TA* __restrict__ A, const bf16* __restrict__ B,
    const bf16* __restrict__ bias, TC* __restrict__ C,
    int M, int N, int K)
{
  __shared__ float As[16][68];
  __shared__ float Bs[16][68];
  const int tid = threadIdx.x;
  const int tx = tid & 15;
  const int ty = tid >> 4;
  const int m0 = blockIdx.y * 64;
  const int n0 = blockIdx.x * 64;

  float acc[4][4] = {};

  for (int k0 = 0; k0 < K; k0 += 16) {
#pragma unroll
    for (int i = 0; i < 4; ++i) {
      int e = tid + 256 * i;
      int m = e >> 4, kk = e & 15;
      float v = 0.f;
      if (m0 + m < M) v = ldf(&A[(size_t)(m0 + m) * K + k0 + kk]);
      As[kk][m] = v;
    }
#pragma unroll
    for (int i = 0; i < 4; ++i) {
      int e = tid + 256 * i;
      if (TRANS_B) {
        int n = e >> 4, kk = e & 15;
        float v = 0.f;
        if (n0 + n < N) v = ldf(&B[(size_t)(n0 + n) * K + k0 + kk]);
        Bs[kk][n] = v;
      } else {
        int kk = e >> 6, n = e & 63;
        float v = 0.f;
        if (n0 + n < N) v = ldf(&B[(size_t)(k0 + kk) * N + n0 + n]);
        Bs[kk][n] = v;
      }
    }
    __syncthreads();
#pragma unroll
    for (int kk = 0; kk < 16; ++kk) {
      const float4 av = *reinterpret_cast<const float4*>(&As[kk][ty * 4]);
      const float4 bv = *reinterpret_cast<const float4*>(&Bs[kk][tx * 4]);
      const float a[4] = {av.x, av.y, av.z, av.w};
      const float b[4] = {bv.x, bv.y, bv.z, bv.w};
#pragma unroll
      for (int i = 0; i < 4; ++i)
#pragma unroll
        for (int j = 0; j < 4; ++j) acc[i][j] += a[i] * b[j];
    }
    __syncthreads();
  }

#pragma unroll
  for (int i = 0; i < 4; ++i) {
    int m = m0 + ty * 4 + i;
    if (m >= M) continue;
#pragma unroll
    for (int j = 0; j < 4; ++j) {
      int n = n0 + tx * 4 + j;
      if (n >= N) continue;
      float v = acc[i][j];
      if (bias) v += b2f(bias[n]);
      if (ACT == ACT_SILU) v = v / (1.f + __expf(-v));
      if (ACT == ACT_SIGMOID) v = 1.f / (1.f + __expf(-v));
      stf(&C[(size_t)m * N + n], v);
    }
  }
}

// Row LayerNorm over width W; optional post-LN add of a bf16 vector.
template <typename TI, typename TO, bool ADD, int W, int BS>
__global__ __launch_bounds__(BS) void ln_kernel(
    const TI* __restrict__ in, const bf16* __restrict__ g, const bf16* __restrict__ b,
    const bf16* __restrict__ addv, TO* __restrict__ out)
{
  __shared__ float red[BS];
  const int row = blockIdx.x;
  const TI* rin = in + (size_t)row * W;
  TO* rout = out + (size_t)row * W;
  const int NP = W / BS;
  float v[NP];
  float s = 0.f;
#pragma unroll
  for (int i = 0; i < NP; ++i) { v[i] = ldf(&rin[threadIdx.x + i * BS]); s += v[i]; }
  red[threadIdx.x] = s; __syncthreads();
  for (int o = BS / 2; o > 0; o >>= 1) {
    if (threadIdx.x < o) red[threadIdx.x] += red[threadIdx.x + o];
    __syncthreads();
  }
  const float mean = red[0] / W;
  __syncthreads();
  float sq = 0.f;
#pragma unroll
  for (int i = 0; i < NP; ++i) { float d = v[i] - mean; sq += d * d; }
  red[threadIdx.x] = sq; __syncthreads();
  for (int o = BS / 2; o > 0; o >>= 1) {
    if (threadIdx.x < o) red[threadIdx.x] += red[threadIdx.x + o];
    __syncthreads();
  }
  const float rstd = rsqrtf(red[0] / W + 1e-5f);
#pragma unroll
  for (int i = 0; i < NP; ++i) {
    int c = threadIdx.x + i * BS;
    float o_ = (v[i] - mean) * rstd * b2f(g[c]) + b2f(b[c]);
    if (ADD) o_ += b2f(addv[c]);
    stf(&rout[c], o_);
  }
}

// ---------------- MFMA attention: one block per (segment, head) -------------
// T = 64(retr) + 4(persist) + 64(xs) = 132, padded to 160. HD = 128. S = 64.
// 256 threads = 4 waves; wave w owns the 16-row s-band w.
__global__ __launch_bounds__(256) void attn_kernel(
    const bf16* __restrict__ qg, const bf16* __restrict__ krg, const bf16* __restrict__ kxg,
    const bf16* __restrict__ kpg, const bf16* __restrict__ vrg, const bf16* __restrict__ vxg,
    const bf16* __restrict__ vpg, bf16* __restrict__ outg)
{
  const int C = 1024;
  __shared__ short qs[4 * 64 * 32];     // [kb][s][32]   (m97 tile layout)
  __shared__ short ksl[4 * 160 * 32];   // [kb][t][32]   (rows >=132 unread data masked)
  __shared__ short vsl[160 * 138];      // [t][d] rows padded to 138 (rows>=132 zeroed)
  __shared__ short psl[5 * 64 * 32];    // [kbt][s][32]  P in A-frag tile layout

  const int tid = threadIdx.x;
  const int seg = blockIdx.x >> 3;
  const int h = blockIdx.x & 7;
  const unsigned short* q = (const unsigned short*)qg;
  const unsigned short* kr = (const unsigned short*)krg;
  const unsigned short* kx = (const unsigned short*)kxg;
  const unsigned short* kp = (const unsigned short*)kpg;
  const unsigned short* vr = (const unsigned short*)vrg;
  const unsigned short* vx = (const unsigned short*)vxg;
  const unsigned short* vp = (const unsigned short*)vpg;
  const size_t segbase = (size_t)seg * 64 * C + (size_t)h * 128;

  // ---- stage Q: 64 rows x 16 chunks of 8 shorts
  for (int ch = tid; ch < 64 * 16; ch += 256) {
    const int row = ch >> 4, k8 = ch & 15;
    const uint4 v = *(const uint4*)(q + segbase + (size_t)row * C + k8 * 8);
    *(uint4*)&qs[(((k8 >> 2) * 64) + row) * 32 + (k8 & 3) * 8] = v;
  }
  // ---- stage K rows 0..131
  for (int ch = tid; ch < 132 * 16; ch += 256) {
    const int t = ch >> 4, k8 = ch & 15;
    const unsigned short* src;
    if (t < 64) src = kr + segbase + (size_t)t * C;
    else if (t < 68) src = kp + (size_t)(t - 64) * C + h * 128;
    else src = kx + segbase + (size_t)(t - 68) * C;
    const uint4 v = *(const uint4*)(src + k8 * 8);
    *(uint4*)&ksl[(((k8 >> 2) * 160) + t) * 32 + (k8 & 3) * 8] = v;
  }
  // ---- stage V rows 0..131 (4B chunks; 138-short row stride)
  for (int ch = tid; ch < 132 * 64; ch += 256) {
    const int t = ch >> 6, k2 = ch & 63;
    const unsigned short* src;
    if (t < 64) src = vr + segbase + (size_t)t * C;
    else if (t < 68) src = vp + (size_t)(t - 64) * C + h * 128;
    else src = vx + segbase + (size_t)(t - 68) * C;
    *(unsigned int*)&vsl[t * 138 + k2 * 2] = *(const unsigned int*)(src + k2 * 2);
  }
  // zero V pad rows 132..159 (prevents 0*NaN in PV mfma)
  for (int ch = tid; ch < 28 * 64; ch += 256) {
    const int t = 132 + (ch >> 6), k2 = ch & 63;
    *(unsigned int*)&vsl[t * 138 + k2 * 2] = 0u;
  }
  __syncthreads();

  const int wave = tid >> 6, lane = tid & 63;
  const int fm = lane & 15;        // col within tile / frag row
  const int fq = lane >> 4;        // quad
  const int s0 = wave * 16;

  // ---- QK^T: wave computes S[s0..s0+15][0..159] as 10 tiles
  f32x4 acc[10];
#pragma unroll
  for (int tt = 0; tt < 10; ++tt) acc[tt] = (f32x4){0.f, 0.f, 0.f, 0.f};
#pragma unroll
  for (int kb = 0; kb < 4; ++kb) {
    const bf16x8 a = *(const bf16x8*)&qs[((kb * 64) + s0 + fm) * 32 + fq * 8];
#pragma unroll
    for (int tt = 0; tt < 10; ++tt) {
      const bf16x8 b = *(const bf16x8*)&ksl[((kb * 160) + tt * 16 + fm) * 32 + fq * 8];
      acc[tt] = __builtin_amdgcn_mfma_f32_16x16x32_bf16(a, b, acc[tt], 0, 0, 0);
    }
  }

  // ---- softmax per row (C/D: col=lane&15, row=fq*4+r), t = tt*16 + fm
  const float scale = 0.08838834764831845f;  // 1/sqrt(128)
#pragma unroll
  for (int r = 0; r < 4; ++r) {
    float m = -3.0e38f;
#pragma unroll
    for (int tt = 0; tt < 10; ++tt) {
      const int t = tt * 16 + fm;
      if (t < 132) m = fmaxf(m, acc[tt][r] * scale);
    }
    for (int d = 1; d < 16; d <<= 1) m = fmaxf(m, __shfl_xor(m, d));
    float sum = 0.f;
#pragma unroll
    for (int tt = 0; tt < 10; ++tt) {
      const int t = tt * 16 + fm;
      float e = 0.f;
      if (t < 132) e = __expf(acc[tt][r] * scale - m);
      acc[tt][r] = e;
      sum += e;
    }
    for (int d = 1; d < 16; d <<= 1) sum += __shfl_xor(sum, d);
    const float inv = 1.f / sum;
    const int s = s0 + fq * 4 + r;
#pragma unroll
    for (int tt = 0; tt < 10; ++tt) {
      const int t = tt * 16 + fm;
      const bf16 pv = __float2bfloat16(acc[tt][r] * inv);
      psl[((t >> 5) * 64 + s) * 32 + (t & 31)] = *(const short*)&pv;
    }
  }
  __syncthreads();

  // ---- PV: out[s-band][128] = P[s-band][160] @ V[160][128]
  bf16x8 pa[5];
#pragma unroll
  for (int kb = 0; kb < 5; ++kb)
    pa[kb] = *(const bf16x8*)&psl[(kb * 64 + s0 + fm) * 32 + fq * 8];

#pragma unroll
  for (int j = 0; j < 8; ++j) {
    f32x4 o = (f32x4){0.f, 0.f, 0.f, 0.f};
    const int d = j * 16 + fm;
#pragma unroll
    for (int kb = 0; kb < 5; ++kb) {
      const int t0 = kb * 32 + fq * 8;
      bf16x8 b;
#pragma unroll
      for (int jj = 0; jj < 8; ++jj) b[jj] = vsl[(t0 + jj) * 138 + d];
      o = __builtin_amdgcn_mfma_f32_16x16x32_bf16(pa[kb], b, o, 0, 0, 0);
    }
#pragma unroll
    for (int r = 0; r < 4; ++r) {
      const int s = s0 + fq * 4 + r;
      outg[segbase + (size_t)s * C + d] = __float2bfloat16(o[r]);
    }
  }
}

// t = gate * ao + x (elementwise)
__global__ __launch_bounds__(256) void combine_kernel(
    const bf16* __restrict__ g, const bf16* __restrict__ a,
    const bf16* __restrict__ x, bf16* __restrict__ o, int n)
{
  int i = blockIdx.x * 256 + threadIdx.x;
  if (i < n)
    o[i] = __float2bfloat16(b2f(g[i]) * b2f(a[i]) + b2f(x[i]));
}

extern "C" void kernel_launch(void* const* d_in, const int* in_sizes, int n_in,
                              void* d_out, int out_size, void* d_ws, size_t ws_size,
                              hipStream_t stream)
{
  (void)n_in; (void)out_size;
  const int R = 16384, Cd = 1024, Md = 128;

  char* ws = (char*)d_ws;
  size_t off = 0;
  auto alloc = [&](size_t bytes) -> void* {
    void* p = ws + off;
    off += (bytes + 255) & ~(size_t)255;
    return p;
  };

  int* flag = (int*)alloc(256);
  bf16* nb[30];
  nb[0] = nullptr;
  for (int i = 1; i < 30; ++i) nb[i] = (bf16*)alloc((size_t)in_sizes[i] * sizeof(bf16));
  bf16* Wkk = (bf16*)alloc((size_t)Cd * Cd * sizeof(bf16));
  bf16* Wvv = (bf16*)alloc((size_t)Cd * Cd * sizeof(bf16));
  bf16* kp  = (bf16*)alloc((size_t)4 * Cd * sizeof(bf16));
  bf16* vp  = (bf16*)alloc((size_t)4 * Cd * sizeof(bf16));
  const size_t fixed_end = off;

  int CR = R;
  while (CR > 512 && (size_t)CR * 14848 + fixed_end + 8192 > ws_size) CR >>= 1;
  const int n_chunks = R / CR;

  const size_t RB = (size_t)CR * Cd * sizeof(bf16);
  bf16* Xc = (bf16*)alloc(RB);
  bf16* A  = (bf16*)alloc(RB);   // q_seg -> v_x
  bf16* Bb = (bf16*)alloc(RB);   // retrieved -> attn out
  bf16* Cc = (bf16*)alloc(RB);   // k_r -> gin -> t
  bf16* Dd = (bf16*)alloc(RB);   // v_r -> gate
  bf16* Ee = (bf16*)alloc(RB);   // k_x
  bf16* G  = (bf16*)alloc(RB);   // q -> ao
  bf16* h1b = (bf16*)alloc((size_t)CR * Md * sizeof(bf16));
  bf16* h2b = (bf16*)alloc((size_t)CR * Md * sizeof(bf16));

  auto grd64 = [](int M_, int N_) {
    return dim3((unsigned)((N_ + 63) / 64), (unsigned)((M_ + 63) / 64));
  };
  auto grd128 = [](int M_, int N_) {
    return dim3((unsigned)(N_ / 128), (unsigned)(M_ / 128));
  };
  dim3 blk(256);

  detect_kernel<<<1, 64, 0, stream>>>((const unsigned short*)d_in[24], flag);
  for (int i = 1; i < 30; ++i) {
    int n = in_sizes[i];
    conv_kernel<<<dim3((n + 255) / 256), blk, 0, stream>>>(d_in[i], nb[i], n, 0, flag);
  }

  const bf16 *pm = nb[1], *Wq = nb[2], *Wk = nb[3], *Wv = nb[4];
  const bf16 *mem_W1 = nb[5], *mem_b1 = nb[6], *ln1g = nb[7], *ln1b = nb[8];
  const bf16 *mem_W2 = nb[9], *mem_b2 = nb[10], *ln2g = nb[11], *ln2b = nb[12];
  const bf16 *mem_oW = nb[13], *mem_ob = nb[14], *mstate = nb[15];
  const bf16 *mhaWq = nb[16], *mhabq = nb[17], *mhaWk = nb[18], *mhabk = nb[19];
  const bf16 *mhaWv = nb[20], *mhabv = nb[21], *mhaWo = nb[22], *mhabo = nb[23];
  const bf16 *gn_g = nb[24], *gn_b = nb[25], *gateW = nb[26], *gateb = nb[27];
  const bf16 *outW = nb[28], *outb = nb[29];

  gemm_kernel<bf16, bf16, ACT_NONE, false><<<grd64(Cd, Cd), blk, 0, stream>>>(mhaWk, Wk, nullptr, Wkk, Cd, Cd, Cd);
  gemm_kernel<bf16, bf16, ACT_NONE, false><<<grd64(Cd, Cd), blk, 0, stream>>>(mhaWv, Wv, nullptr, Wvv, Cd, Cd, Cd);
  gemm_kernel<bf16, bf16, ACT_NONE, true><<<grd64(4, Cd), blk, 0, stream>>>(pm, Wkk, mhabk, kp, 4, Cd, Cd);
  gemm_kernel<bf16, bf16, ACT_NONE, true><<<grd64(4, Cd), blk, 0, stream>>>(pm, Wvv, mhabv, vp, 4, Cd, Cd);

  for (int c = 0; c < n_chunks; ++c) {
    float* outc = (float*)d_out + (size_t)c * CR * Cd;
    const int n = CR * Cd;
    conv_kernel<<<dim3((n + 255) / 256), blk, 0, stream>>>(
        d_in[0], Xc, n, (size_t)c * CR * Cd, flag);

    // q_seg -> memory net -> retrieved (Bb)
    mgemm<bf16, ACT_NONE, false><<<grd128(CR, Cd), blk, 0, stream>>>(Xc, Wq, nullptr, A, CR, Cd, Cd);
    mgemm<bf16, ACT_SILU, true><<<grd128(CR, Md), blk, 0, stream>>>(A, mem_W1, mem_b1, h1b, CR, Md, Cd);
    ln_kernel<bf16, bf16, false, 128, 128><<<CR, 128, 0, stream>>>(h1b, ln1g, ln1b, nullptr, h2b);
    mgemm<bf16, ACT_NONE, true><<<grd128(CR, Md), blk, 0, stream>>>(h2b, mem_W2, mem_b2, h1b, CR, Md, Md);
    ln_kernel<bf16, bf16, true, 128, 128><<<CR, 128, 0, stream>>>(h1b, ln2g, ln2b, mstate, h2b);
    mgemm<bf16, ACT_NONE, true><<<grd128(CR, Cd), blk, 0, stream>>>(h2b, mem_oW, mem_ob, Bb, CR, Cd, Md);

    // QKV projections
    mgemm<bf16, ACT_NONE, true><<<grd128(CR, Cd), blk, 0, stream>>>(A, mhaWq, mhabq, G, CR, Cd, Cd);   // q
    mgemm<bf16, ACT_NONE, true><<<grd128(CR, Cd), blk, 0, stream>>>(Bb, Wkk, mhabk, Cc, CR, Cd, Cd);   // k_r
    mgemm<bf16, ACT_NONE, true><<<grd128(CR, Cd), blk, 0, stream>>>(Bb, Wvv, mhabv, Dd, CR, Cd, Cd);   // v_r
    mgemm<bf16, ACT_NONE, true><<<grd128(CR, Cd), blk, 0, stream>>>(Xc, Wkk, mhabk, Ee, CR, Cd, Cd);   // k_x
    mgemm<bf16, ACT_NONE, true><<<grd128(CR, Cd), blk, 0, stream>>>(Xc, Wvv, mhabv, A, CR, Cd, Cd);    // v_x

    attn_kernel<<<dim3((CR / 64) * 8), blk, 0, stream>>>(G, Cc, Ee, kp, Dd, A, vp, Bb);

    mgemm<bf16, ACT_NONE, true><<<grd128(CR, Cd), blk, 0, stream>>>(Bb, mhaWo, mhabo, G, CR, Cd, Cd);      // ao
    ln_kernel<bf16, bf16, false, 1024, 256><<<CR, 256, 0, stream>>>(G, gn_g, gn_b, nullptr, Cc);           // gin
    mgemm<bf16, ACT_SIGMOID, true><<<grd128(CR, Cd), blk, 0, stream>>>(Cc, gateW, gateb, Dd, CR, Cd, Cd);  // gate
    combine_kernel<<<dim3(n / 256), blk, 0, stream>>>(Dd, G, Xc, Cc, n);                                   // t
    mgemm<float, ACT_NONE, true><<<grd128(CR, Cd), blk, 0, stream>>>(Cc, outW, outb, outc, CR, Cd, Cd);
  }
}